// Round 1
// baseline (791.905 us; speedup 1.0000x reference)
//
#include <hip/hip_runtime.h>
#include <hip/hip_bf16.h>
#include <cstdint>
#include <cstddef>

#define D 768
#define BATCH 8
#define LC 2048
#define LQ 1024
#define SCALE 0.03608439182435161f /* 1/sqrt(768) */

typedef __attribute__((ext_vector_type(8))) short short8;
typedef __attribute__((ext_vector_type(4))) float floatx4;

__device__ __forceinline__ short f2bf(float f) {
    union { float f; uint32_t u; } v; v.f = f;
    uint32_t r = v.u + 0x7fffu + ((v.u >> 16) & 1u);
    return (short)(r >> 16);
}

// ---------------- cast fp32 -> bf16 (vectorized x4) ----------------
__global__ void cast_bf16_kernel(const float* __restrict__ src, short* __restrict__ dst, int n4) {
    int i = blockIdx.x * 256 + threadIdx.x;
    if (i >= n4) return;
    float4 v = reinterpret_cast<const float4*>(src)[i];
    short4 o;
    o.x = f2bf(v.x); o.y = f2bf(v.y); o.z = f2bf(v.z); o.w = f2bf(v.w);
    reinterpret_cast<short4*>(dst)[i] = o;
}

// ---------------- transpose qh [B,LQ,D] fp32 -> qhT [B,D,LQ] bf16 ----------------
__global__ void transpose_qh_kernel(const float* __restrict__ qh, short* __restrict__ qhT) {
    __shared__ float tile[32][33];
    const int b = blockIdx.z;
    const int q0 = blockIdx.x * 32, d0 = blockIdx.y * 32;
    const int t = threadIdx.x;
    const int r = t >> 3, c = (t & 7) * 4;
    const float4 v = *reinterpret_cast<const float4*>(qh + ((size_t)b * LQ + q0 + r) * D + d0 + c);
    tile[r][c] = v.x; tile[r][c + 1] = v.y; tile[r][c + 2] = v.z; tile[r][c + 3] = v.w;
    __syncthreads();
    short4 o;
    o.x = f2bf(tile[c][r]); o.y = f2bf(tile[c + 1][r]);
    o.z = f2bf(tile[c + 2][r]); o.w = f2bf(tile[c + 3][r]);
    *reinterpret_cast<short4*>(qhT + ((size_t)b * D + d0 + r) * LQ + q0 + c) = o;
}

// ---------------- GEMM1: query[m,n] = sum_k qh_b[m,k]*W_b[n,k] + bias[n] ----------------
// M=8192, N=768, K=768. 128x128 tile, 4 waves each 64x64.
__global__ __launch_bounds__(256, 2) void gemm1_kernel(
    const short* __restrict__ A, const short* __restrict__ W,
    const float* __restrict__ bias, short* __restrict__ Q) {
    __shared__ short sA[128 * 40];
    __shared__ short sB[128 * 40];
    const int m0 = blockIdx.x * 128;
    const int n0 = blockIdx.y * 128;
    const int tid = threadIdx.x;
    const int w = tid >> 6, lane = tid & 63, l15 = lane & 15, quad = lane >> 4;
    const int wm = (w >> 1) * 64, wn = (w & 1) * 64;
    floatx4 acc[4][4];
#pragma unroll
    for (int i = 0; i < 4; ++i)
#pragma unroll
        for (int j = 0; j < 4; ++j) { floatx4 z = {0.f, 0.f, 0.f, 0.f}; acc[i][j] = z; }

    const int lrow = tid >> 2;        // 0..63
    const int lcol = (tid & 3) * 8;   // 0,8,16,24

    for (int k0 = 0; k0 < 768; k0 += 32) {
#pragma unroll
        for (int h = 0; h < 2; ++h) {
            int row = lrow + h * 64;
            short8 va = *reinterpret_cast<const short8*>(A + (size_t)(m0 + row) * 768 + k0 + lcol);
            *reinterpret_cast<short8*>(&sA[row * 40 + lcol]) = va;
            short8 vb = *reinterpret_cast<const short8*>(W + (size_t)(n0 + row) * 768 + k0 + lcol);
            *reinterpret_cast<short8*>(&sB[row * 40 + lcol]) = vb;
        }
        __syncthreads();
        short8 af[4], bf[4];
#pragma unroll
        for (int mt = 0; mt < 4; ++mt)
            af[mt] = *reinterpret_cast<const short8*>(&sA[(wm + mt * 16 + l15) * 40 + quad * 8]);
#pragma unroll
        for (int nt = 0; nt < 4; ++nt)
            bf[nt] = *reinterpret_cast<const short8*>(&sB[(wn + nt * 16 + l15) * 40 + quad * 8]);
#pragma unroll
        for (int mt = 0; mt < 4; ++mt)
#pragma unroll
            for (int nt = 0; nt < 4; ++nt)
                acc[mt][nt] = __builtin_amdgcn_mfma_f32_16x16x32_bf16(af[mt], bf[nt], acc[mt][nt], 0, 0, 0);
        __syncthreads();
    }
    float bv[4];
#pragma unroll
    for (int nt = 0; nt < 4; ++nt) bv[nt] = bias[n0 + wn + nt * 16 + l15];
#pragma unroll
    for (int mt = 0; mt < 4; ++mt)
#pragma unroll
        for (int r = 0; r < 4; ++r) {
            int row = m0 + wm + mt * 16 + quad * 4 + r;
#pragma unroll
            for (int nt = 0; nt < 4; ++nt)
                Q[(size_t)row * 768 + n0 + wn + nt * 16 + l15] = f2bf(acc[mt][nt][r] + bv[nt]);
        }
}

// ---------------- copy context into out[:, :, 0:768] ----------------
__global__ void copy_ctx_kernel(const float* __restrict__ ctx, float* __restrict__ out) {
    size_t i = (size_t)blockIdx.x * 256 + threadIdx.x; // float4 index, total 3145728
    size_t row = i / 192;
    size_t c4 = i % 192;
    float4 v = reinterpret_cast<const float4*>(ctx)[i];
    reinterpret_cast<float4*>(out)[row * 384 + c4] = v;
}

// ---------------- fused flash attention ----------------
// grid (LC/64, B), block 256 (4 waves). Wave w owns ctx rows [c0+16w, c0+16w+16).
__global__ __launch_bounds__(256, 1) void flash_kernel(
    const float* __restrict__ ctx, const short* __restrict__ query_b,
    const short* __restrict__ qhT, const int* __restrict__ qmask,
    float* __restrict__ out) {
    __shared__ short sP[4][16 * 72];
    const int b = blockIdx.y;
    const int c0 = blockIdx.x * 64;
    const int tid = threadIdx.x;
    const int w = tid >> 6;
    const int lane = tid & 63;
    const int l15 = lane & 15;
    const int quad = lane >> 4;
    const int myrow = c0 + w * 16 + l15;   // A-operand row for this lane

    // Load this wave's 16 context rows as 24 MFMA A-fragments (fp32 -> bf16 in regs)
    short8 afr[24];
    {
        const float* src = ctx + ((size_t)b * LC + myrow) * D + quad * 8;
#pragma unroll
        for (int ks = 0; ks < 24; ++ks) {
            float4 v0 = *reinterpret_cast<const float4*>(src + ks * 32);
            float4 v1 = *reinterpret_cast<const float4*>(src + ks * 32 + 4);
            short8 a;
            a[0] = f2bf(v0.x); a[1] = f2bf(v0.y); a[2] = f2bf(v0.z); a[3] = f2bf(v0.w);
            a[4] = f2bf(v1.x); a[5] = f2bf(v1.y); a[6] = f2bf(v1.z); a[7] = f2bf(v1.w);
            afr[ks] = a;
        }
    }

    float m_i[4], l_i[4];
#pragma unroll
    for (int r = 0; r < 4; ++r) { m_i[r] = -__builtin_inff(); l_i[r] = 0.f; }
    floatx4 o[48];
#pragma unroll
    for (int i = 0; i < 48; ++i) { floatx4 z = {0.f, 0.f, 0.f, 0.f}; o[i] = z; }

    const short* Qb = query_b + (size_t)b * LQ * D;
    const short* Vt = qhT + (size_t)b * D * LQ;
    const int* mk = qmask + b * LQ;
    short* Pw = &sP[w][0];

    for (int q0 = 0; q0 < LQ; q0 += 64) {
        // ---- S = C(16) x Q_chunk(64)^T, K=768 ----
        floatx4 s[4];
#pragma unroll
        for (int t = 0; t < 4; ++t) { floatx4 z = {0.f, 0.f, 0.f, 0.f}; s[t] = z; }
#pragma unroll
        for (int ks = 0; ks < 24; ++ks) {
#pragma unroll
            for (int t = 0; t < 4; ++t) {
                short8 bfr = *reinterpret_cast<const short8*>(
                    Qb + (size_t)(q0 + t * 16 + l15) * D + ks * 32 + quad * 8);
                s[t] = __builtin_amdgcn_mfma_f32_16x16x32_bf16(afr[ks], bfr, s[t], 0, 0, 0);
            }
        }
        // ---- scale + mask + online softmax (rows are wave-local) ----
        float rowmax[4] = {-1e38f, -1e38f, -1e38f, -1e38f};
#pragma unroll
        for (int t = 0; t < 4; ++t) {
            const bool valid = (mk[q0 + t * 16 + l15] != 0);
#pragma unroll
            for (int r = 0; r < 4; ++r) {
                float sv = valid ? s[t][r] * SCALE : -1e30f;
                s[t][r] = sv;
                rowmax[r] = fmaxf(rowmax[r], sv);
            }
        }
#pragma unroll
        for (int off = 1; off < 16; off <<= 1)
#pragma unroll
            for (int r = 0; r < 4; ++r)
                rowmax[r] = fmaxf(rowmax[r], __shfl_xor(rowmax[r], off, 64));
        float alpha[4];
#pragma unroll
        for (int r = 0; r < 4; ++r) {
            float mnew = fmaxf(m_i[r], rowmax[r]);
            alpha[r] = __expf(m_i[r] - mnew);
            m_i[r] = mnew;
        }
        float rowsum[4] = {0.f, 0.f, 0.f, 0.f};
#pragma unroll
        for (int t = 0; t < 4; ++t)
#pragma unroll
            for (int r = 0; r < 4; ++r) {
                float pv = __expf(s[t][r] - m_i[r]);
                s[t][r] = pv;
                rowsum[r] += pv;
            }
#pragma unroll
        for (int off = 1; off < 16; off <<= 1)
#pragma unroll
            for (int r = 0; r < 4; ++r)
                rowsum[r] += __shfl_xor(rowsum[r], off, 64);
#pragma unroll
        for (int r = 0; r < 4; ++r) l_i[r] = l_i[r] * alpha[r] + rowsum[r];
        // rescale O
#pragma unroll
        for (int i = 0; i < 48; ++i)
#pragma unroll
            for (int r = 0; r < 4; ++r) o[i][r] *= alpha[r];
        // P (C-layout) -> LDS -> A-layout
#pragma unroll
        for (int t = 0; t < 4; ++t)
#pragma unroll
            for (int r = 0; r < 4; ++r)
                Pw[(quad * 4 + r) * 72 + t * 16 + l15] = f2bf(s[t][r]);
        __syncthreads();
        // ---- O += P(16x64) @ V(64x768) ----
#pragma unroll
        for (int kk = 0; kk < 2; ++kk) {
            short8 ap = *reinterpret_cast<const short8*>(&Pw[l15 * 72 + kk * 32 + quad * 8]);
#pragma unroll
            for (int nt = 0; nt < 48; ++nt) {
                short8 bfr = *reinterpret_cast<const short8*>(
                    Vt + (size_t)(nt * 16 + l15) * LQ + q0 + kk * 32 + quad * 8);
                o[nt] = __builtin_amdgcn_mfma_f32_16x16x32_bf16(ap, bfr, o[nt], 0, 0, 0);
            }
        }
        __syncthreads();
    }
    // epilogue: out[b, row, 768 + d] = o / l
#pragma unroll
    for (int r = 0; r < 4; ++r) {
        const float inv = 1.0f / l_i[r];
        float* orow = out + ((size_t)b * LC + (c0 + w * 16 + quad * 4 + r)) * 1536 + 768;
#pragma unroll
        for (int nt = 0; nt < 48; ++nt)
            orow[nt * 16 + l15] = o[nt][r] * inv;
    }
}

extern "C" void kernel_launch(void* const* d_in, const int* in_sizes, int n_in,
                              void* d_out, int out_size, void* d_ws, size_t ws_size,
                              hipStream_t stream) {
    const float* ctx = (const float*)d_in[0];
    const float* qh = (const float*)d_in[2];
    const int* qmask = (const int*)d_in[3];
    const float* Wf = (const float*)d_in[4];
    const float* bias = (const float*)d_in[5];
    float* out = (float*)d_out;

    char* ws = (char*)d_ws;
    short* qh_b = (short*)(ws);                    // 12,582,912 B
    short* W_b = (short*)(ws + 12582912);          //  1,179,648 B
    short* query_b = (short*)(ws + 13762560);      // 12,582,912 B
    short* qhT = (short*)(ws + 26345472);          // 12,582,912 B  (total 38.9 MB)

    cast_bf16_kernel<<<6144, 256, 0, stream>>>(qh, qh_b, 1572864);
    cast_bf16_kernel<<<576, 256, 0, stream>>>(Wf, W_b, 147456);
    transpose_qh_kernel<<<dim3(32, 24, 8), 256, 0, stream>>>(qh, qhT);
    gemm1_kernel<<<dim3(64, 6), 256, 0, stream>>>(qh_b, W_b, bias, query_b);
    copy_ctx_kernel<<<12288, 256, 0, stream>>>(ctx, out);
    flash_kernel<<<dim3(32, 8), 256, 0, stream>>>(ctx, query_b, qhT, qmask, out);
}

// Round 2
// 357.099 us; speedup vs baseline: 2.2176x; 2.2176x over previous
//
#include <hip/hip_runtime.h>
#include <hip/hip_bf16.h>
#include <cstdint>
#include <cstddef>

#define D 768
#define BATCH 8
#define LC 2048
#define LQ 1024
#define SCALE 0.03608439182435161f /* 1/sqrt(768) */

typedef __attribute__((ext_vector_type(8))) short short8;
typedef __attribute__((ext_vector_type(4))) float floatx4;

__device__ __forceinline__ short f2bf(float f) {
    union { float f; uint32_t u; } v; v.f = f;
    uint32_t r = v.u + 0x7fffu + ((v.u >> 16) & 1u);
    return (short)(r >> 16);
}

// ---------------- cast fp32 -> bf16 (vectorized x4) ----------------
__global__ void cast_bf16_kernel(const float* __restrict__ src, short* __restrict__ dst, int n4) {
    int i = blockIdx.x * 256 + threadIdx.x;
    if (i >= n4) return;
    float4 v = reinterpret_cast<const float4*>(src)[i];
    short4 o;
    o.x = f2bf(v.x); o.y = f2bf(v.y); o.z = f2bf(v.z); o.w = f2bf(v.w);
    reinterpret_cast<short4*>(dst)[i] = o;
}

// ---------------- transpose qh [B,LQ,D] fp32 -> qhT [B,D,LQ] bf16 ----------------
__global__ void transpose_qh_kernel(const float* __restrict__ qh, short* __restrict__ qhT) {
    __shared__ float tile[32][33];
    const int b = blockIdx.z;
    const int q0 = blockIdx.x * 32, d0 = blockIdx.y * 32;
    const int t = threadIdx.x;
    const int r = t >> 3, c = (t & 7) * 4;
    const float4 v = *reinterpret_cast<const float4*>(qh + ((size_t)b * LQ + q0 + r) * D + d0 + c);
    tile[r][c] = v.x; tile[r][c + 1] = v.y; tile[r][c + 2] = v.z; tile[r][c + 3] = v.w;
    __syncthreads();
    short4 o;
    o.x = f2bf(tile[c][r]); o.y = f2bf(tile[c + 1][r]);
    o.z = f2bf(tile[c + 2][r]); o.w = f2bf(tile[c + 3][r]);
    *reinterpret_cast<short4*>(qhT + ((size_t)b * D + d0 + r) * LQ + q0 + c) = o;
}

// ---------------- GEMM1: query[m,n] = sum_k qh_b[m,k]*W_b[n,k] + bias[n] ----------------
__global__ __launch_bounds__(256, 2) void gemm1_kernel(
    const short* __restrict__ A, const short* __restrict__ W,
    const float* __restrict__ bias, short* __restrict__ Q) {
    __shared__ short sA[128 * 40];
    __shared__ short sB[128 * 40];
    const int m0 = blockIdx.x * 128;
    const int n0 = blockIdx.y * 128;
    const int tid = threadIdx.x;
    const int w = tid >> 6, lane = tid & 63, l15 = lane & 15, quad = lane >> 4;
    const int wm = (w >> 1) * 64, wn = (w & 1) * 64;
    floatx4 acc[4][4];
#pragma unroll
    for (int i = 0; i < 4; ++i)
#pragma unroll
        for (int j = 0; j < 4; ++j) { floatx4 z = {0.f, 0.f, 0.f, 0.f}; acc[i][j] = z; }

    const int lrow = tid >> 2;
    const int lcol = (tid & 3) * 8;

    for (int k0 = 0; k0 < 768; k0 += 32) {
#pragma unroll
        for (int h = 0; h < 2; ++h) {
            int row = lrow + h * 64;
            short8 va = *reinterpret_cast<const short8*>(A + (size_t)(m0 + row) * 768 + k0 + lcol);
            *reinterpret_cast<short8*>(&sA[row * 40 + lcol]) = va;
            short8 vb = *reinterpret_cast<const short8*>(W + (size_t)(n0 + row) * 768 + k0 + lcol);
            *reinterpret_cast<short8*>(&sB[row * 40 + lcol]) = vb;
        }
        __syncthreads();
        short8 af[4], bf[4];
#pragma unroll
        for (int mt = 0; mt < 4; ++mt)
            af[mt] = *reinterpret_cast<const short8*>(&sA[(wm + mt * 16 + l15) * 40 + quad * 8]);
#pragma unroll
        for (int nt = 0; nt < 4; ++nt)
            bf[nt] = *reinterpret_cast<const short8*>(&sB[(wn + nt * 16 + l15) * 40 + quad * 8]);
#pragma unroll
        for (int mt = 0; mt < 4; ++mt)
#pragma unroll
            for (int nt = 0; nt < 4; ++nt)
                acc[mt][nt] = __builtin_amdgcn_mfma_f32_16x16x32_bf16(af[mt], bf[nt], acc[mt][nt], 0, 0, 0);
        __syncthreads();
    }
    float bv[4];
#pragma unroll
    for (int nt = 0; nt < 4; ++nt) bv[nt] = bias[n0 + wn + nt * 16 + l15];
#pragma unroll
    for (int mt = 0; mt < 4; ++mt)
#pragma unroll
        for (int r = 0; r < 4; ++r) {
            int row = m0 + wm + mt * 16 + quad * 4 + r;
#pragma unroll
            for (int nt = 0; nt < 4; ++nt)
                Q[(size_t)row * 768 + n0 + wn + nt * 16 + l15] = f2bf(acc[mt][nt][r] + bv[nt]);
        }
}

// ---------------- ctx pass: copy ctx into out[:, :, 0:768] AND cast to bf16 ----------------
__global__ void ctx_pass_kernel(const float* __restrict__ ctx, float* __restrict__ out,
                                short* __restrict__ ctxb) {
    size_t i = (size_t)blockIdx.x * 256 + threadIdx.x; // float4 index, total 3145728
    size_t row = i / 192;
    size_t c4 = i % 192;
    float4 v = reinterpret_cast<const float4*>(ctx)[i];
    reinterpret_cast<float4*>(out)[row * 384 + c4] = v;
    short4 o;
    o.x = f2bf(v.x); o.y = f2bf(v.y); o.z = f2bf(v.z); o.w = f2bf(v.w);
    reinterpret_cast<short4*>(ctxb)[i] = o;
}

// ---------------- K1: scores + masked softmax -> P (bf16, normalized) ----------------
// grid (LC/32, B), block 512 (8 waves). Block owns 32 ctx rows x all 1024 q cols.
// Wave w covers cols [128w, 128w+128). No barriers in the K loop.
__global__ __launch_bounds__(512, 4) void scores_kernel(
    const short* __restrict__ ctxb, const short* __restrict__ query_b,
    const int* __restrict__ qmask, short* __restrict__ P) {
    __shared__ float redM[8][32];
    __shared__ float redS[8][32];
    const int b = blockIdx.y;
    const int c0 = blockIdx.x * 32;
    const int tid = threadIdx.x;
    const int w = tid >> 6, lane = tid & 63, l15 = lane & 15, quad = lane >> 4;
    const int n0 = w * 128;
    const short* Ab = ctxb + ((size_t)b * LC + c0) * D;
    const short* Bb = query_b + ((size_t)b * LQ + n0) * D;

    floatx4 acc[2][8];
#pragma unroll
    for (int mt = 0; mt < 2; ++mt)
#pragma unroll
        for (int nt = 0; nt < 8; ++nt) { floatx4 z = {0.f, 0.f, 0.f, 0.f}; acc[mt][nt] = z; }

    for (int k0 = 0; k0 < D; k0 += 32) {
        short8 af[2];
#pragma unroll
        for (int mt = 0; mt < 2; ++mt)
            af[mt] = *reinterpret_cast<const short8*>(Ab + (size_t)(mt * 16 + l15) * D + k0 + quad * 8);
#pragma unroll
        for (int nt = 0; nt < 8; ++nt) {
            short8 bf = *reinterpret_cast<const short8*>(Bb + (size_t)(nt * 16 + l15) * D + k0 + quad * 8);
            acc[0][nt] = __builtin_amdgcn_mfma_f32_16x16x32_bf16(af[0], bf, acc[0][nt], 0, 0, 0);
            acc[1][nt] = __builtin_amdgcn_mfma_f32_16x16x32_bf16(af[1], bf, acc[1][nt], 0, 0, 0);
        }
    }

    // scale + mask + per-lane partial row max (rows: mt*16 + quad*4 + r)
    const int* mk = qmask + b * LQ;
    float pm[2][4];
#pragma unroll
    for (int mt = 0; mt < 2; ++mt)
#pragma unroll
        for (int r = 0; r < 4; ++r) pm[mt][r] = -1e38f;
#pragma unroll
    for (int nt = 0; nt < 8; ++nt) {
        const bool valid = (mk[n0 + nt * 16 + l15] != 0);
#pragma unroll
        for (int mt = 0; mt < 2; ++mt)
#pragma unroll
            for (int r = 0; r < 4; ++r) {
                float x = valid ? acc[mt][nt][r] * SCALE : -1e30f;
                acc[mt][nt][r] = x;
                pm[mt][r] = fmaxf(pm[mt][r], x);
            }
    }
#pragma unroll
    for (int off = 1; off < 16; off <<= 1)
#pragma unroll
        for (int mt = 0; mt < 2; ++mt)
#pragma unroll
            for (int r = 0; r < 4; ++r)
                pm[mt][r] = fmaxf(pm[mt][r], __shfl_xor(pm[mt][r], off, 64));
    if (l15 == 0) {
#pragma unroll
        for (int mt = 0; mt < 2; ++mt)
#pragma unroll
            for (int r = 0; r < 4; ++r)
                redM[w][mt * 16 + quad * 4 + r] = pm[mt][r];
    }
    __syncthreads();
    float M[2][4];
#pragma unroll
    for (int mt = 0; mt < 2; ++mt)
#pragma unroll
        for (int r = 0; r < 4; ++r) {
            float m = -1e38f;
#pragma unroll
            for (int ww = 0; ww < 8; ++ww) m = fmaxf(m, redM[ww][mt * 16 + quad * 4 + r]);
            M[mt][r] = m;
        }
    float ps[2][4] = {{0.f, 0.f, 0.f, 0.f}, {0.f, 0.f, 0.f, 0.f}};
#pragma unroll
    for (int nt = 0; nt < 8; ++nt)
#pragma unroll
        for (int mt = 0; mt < 2; ++mt)
#pragma unroll
            for (int r = 0; r < 4; ++r) {
                float p = __expf(acc[mt][nt][r] - M[mt][r]);
                acc[mt][nt][r] = p;
                ps[mt][r] += p;
            }
#pragma unroll
    for (int off = 1; off < 16; off <<= 1)
#pragma unroll
        for (int mt = 0; mt < 2; ++mt)
#pragma unroll
            for (int r = 0; r < 4; ++r)
                ps[mt][r] += __shfl_xor(ps[mt][r], off, 64);
    if (l15 == 0) {
#pragma unroll
        for (int mt = 0; mt < 2; ++mt)
#pragma unroll
            for (int r = 0; r < 4; ++r)
                redS[w][mt * 16 + quad * 4 + r] = ps[mt][r];
    }
    __syncthreads();
    float inv[2][4];
#pragma unroll
    for (int mt = 0; mt < 2; ++mt)
#pragma unroll
        for (int r = 0; r < 4; ++r) {
            float s = 0.f;
#pragma unroll
            for (int ww = 0; ww < 8; ++ww) s += redS[ww][mt * 16 + quad * 4 + r];
            inv[mt][r] = 1.0f / s;
        }
    // write normalized P (bf16)
    short* Pb = P + ((size_t)b * LC + c0) * LQ;
#pragma unroll
    for (int mt = 0; mt < 2; ++mt)
#pragma unroll
        for (int r = 0; r < 4; ++r) {
            short* prow = Pb + (size_t)(mt * 16 + quad * 4 + r) * LQ + n0;
#pragma unroll
            for (int nt = 0; nt < 8; ++nt)
                prow[nt * 16 + l15] = f2bf(acc[mt][nt][r] * inv[mt][r]);
        }
}

// ---------------- K2: attn_out = P @ qh  (A=P [LC,LQ], B=qhT [D,LQ], K=LQ) ----------------
__global__ __launch_bounds__(256, 2) void gemm2_kernel(
    const short* __restrict__ P, const short* __restrict__ qhT,
    float* __restrict__ out) {
    __shared__ short sA[128 * 40];
    __shared__ short sB[128 * 40];
    const int b = blockIdx.z;
    const int m0 = blockIdx.x * 128;
    const int n0 = blockIdx.y * 128;
    const int tid = threadIdx.x;
    const int w = tid >> 6, lane = tid & 63, l15 = lane & 15, quad = lane >> 4;
    const int wm = (w >> 1) * 64, wn = (w & 1) * 64;
    const short* Ab = P + (size_t)b * LC * LQ;
    const short* Bb = qhT + (size_t)b * D * LQ;
    floatx4 acc[4][4];
#pragma unroll
    for (int i = 0; i < 4; ++i)
#pragma unroll
        for (int j = 0; j < 4; ++j) { floatx4 z = {0.f, 0.f, 0.f, 0.f}; acc[i][j] = z; }

    const int lrow = tid >> 2;
    const int lcol = (tid & 3) * 8;

    for (int k0 = 0; k0 < LQ; k0 += 32) {
#pragma unroll
        for (int h = 0; h < 2; ++h) {
            int row = lrow + h * 64;
            short8 va = *reinterpret_cast<const short8*>(Ab + (size_t)(m0 + row) * LQ + k0 + lcol);
            *reinterpret_cast<short8*>(&sA[row * 40 + lcol]) = va;
            short8 vb = *reinterpret_cast<const short8*>(Bb + (size_t)(n0 + row) * LQ + k0 + lcol);
            *reinterpret_cast<short8*>(&sB[row * 40 + lcol]) = vb;
        }
        __syncthreads();
        short8 af[4], bf[4];
#pragma unroll
        for (int mt = 0; mt < 4; ++mt)
            af[mt] = *reinterpret_cast<const short8*>(&sA[(wm + mt * 16 + l15) * 40 + quad * 8]);
#pragma unroll
        for (int nt = 0; nt < 4; ++nt)
            bf[nt] = *reinterpret_cast<const short8*>(&sB[(wn + nt * 16 + l15) * 40 + quad * 8]);
#pragma unroll
        for (int mt = 0; mt < 4; ++mt)
#pragma unroll
            for (int nt = 0; nt < 4; ++nt)
                acc[mt][nt] = __builtin_amdgcn_mfma_f32_16x16x32_bf16(af[mt], bf[nt], acc[mt][nt], 0, 0, 0);
        __syncthreads();
    }
#pragma unroll
    for (int mt = 0; mt < 4; ++mt)
#pragma unroll
        for (int r = 0; r < 4; ++r) {
            size_t row = (size_t)b * LC + m0 + wm + mt * 16 + quad * 4 + r;
#pragma unroll
            for (int nt = 0; nt < 4; ++nt)
                out[row * 1536 + 768 + n0 + wn + nt * 16 + l15] = acc[mt][nt][r];
        }
}

extern "C" void kernel_launch(void* const* d_in, const int* in_sizes, int n_in,
                              void* d_out, int out_size, void* d_ws, size_t ws_size,
                              hipStream_t stream) {
    const float* ctx = (const float*)d_in[0];
    const float* qh = (const float*)d_in[2];
    const int* qmask = (const int*)d_in[3];
    const float* Wf = (const float*)d_in[4];
    const float* bias = (const float*)d_in[5];
    float* out = (float*)d_out;

    char* ws = (char*)d_ws;
    short* W_b     = (short*)(ws);                  //  1,179,648 B
    short* query_b = (short*)(ws + 1179648);        // 12,582,912 B
    short* qhT     = (short*)(ws + 13762560);       // 12,582,912 B
    short* ctx_b   = (short*)(ws + 26345472);       // 25,165,824 B
    short* P       = (short*)(ws + 51511296);       // 33,554,432 B -> end 85,065,728
    short* qh_b    = (short*)(ws + 51511296);       // alias with P (dead before K1 writes P)

    cast_bf16_kernel<<<576, 256, 0, stream>>>(Wf, W_b, 147456);
    cast_bf16_kernel<<<6144, 256, 0, stream>>>(qh, qh_b, 1572864);
    transpose_qh_kernel<<<dim3(32, 24, 8), 256, 0, stream>>>(qh, qhT);
    gemm1_kernel<<<dim3(64, 6), 256, 0, stream>>>(qh_b, W_b, bias, query_b);
    ctx_pass_kernel<<<12288, 256, 0, stream>>>(ctx, out, ctx_b);
    scores_kernel<<<dim3(64, 8), 512, 0, stream>>>(ctx_b, query_b, qmask, P);
    gemm2_kernel<<<dim3(16, 6, 8), 256, 0, stream>>>(P, qhT, out);
}

// Round 4
// 295.629 us; speedup vs baseline: 2.6787x; 1.2079x over previous
//
#include <hip/hip_runtime.h>
#include <hip/hip_bf16.h>
#include <cstdint>
#include <cstddef>

#define D 768
#define BATCH 8
#define LC 2048
#define LQ 1024
#define SCALE 0.03608439182435161f /* 1/sqrt(768) */

typedef __attribute__((ext_vector_type(8))) short short8;
typedef __attribute__((ext_vector_type(4))) float floatx4;

__device__ __forceinline__ short f2bf(float f) {
    union { float f; uint32_t u; } v; v.f = f;
    uint32_t r = v.u + 0x7fffu + ((v.u >> 16) & 1u);
    return (short)(r >> 16);
}
__device__ __forceinline__ float bf2f(short s) {
    union { uint32_t u; float f; } v; v.u = ((uint32_t)(uint16_t)s) << 16;
    return v.f;
}

// ---- async global->LDS, 16B per lane (cast through uintptr_t to switch addrspace) ----
__device__ __forceinline__ void gl_lds16(const short* g, short* l) {
    __builtin_amdgcn_global_load_lds(
        reinterpret_cast<const __attribute__((address_space(1))) unsigned int*>(
            reinterpret_cast<uintptr_t>(g)),
        reinterpret_cast<__attribute__((address_space(3))) unsigned int*>(
            reinterpret_cast<uintptr_t>(l)),
        16, 0, 0);
}

// stage a 128x32 bf16 tile (rows m0..m0+128, cols k0..k0+32) into lds[128][32]
__device__ __forceinline__ void stage_tile(const short* gbase, int ld, int m0, int k0,
                                           short* lds, int tid) {
    const int r = tid >> 2, kc = (tid & 3) * 8;
    const short* g0 = gbase + (size_t)(m0 + r) * ld + k0 + kc;
    const short* g1 = gbase + (size_t)(m0 + r + 64) * ld + k0 + kc;
    gl_lds16(g0, lds + tid * 8);
    gl_lds16(g1, lds + 2048 + tid * 8);
}

// m97-structure K-loop: C[128,128] += A[128,K] * B[128,K]^T, acc per wave 4x4 frags
__device__ __forceinline__ void mfma_tile_loop(
    const short* Ab, const short* Bb, int lda, int ldb, int K, int m0, int n0,
    short* sA, short* sB, int tid, floatx4 acc[4][4]) {
    const int w = tid >> 6, lane = tid & 63, l15 = lane & 15, quad = lane >> 4;
    const int wm = (w >> 1) * 64, wn = (w & 1) * 64;
    for (int k0 = 0; k0 < K; k0 += 32) {
        stage_tile(Ab, lda, m0, k0, sA, tid);
        stage_tile(Bb, ldb, n0, k0, sB, tid);
        __syncthreads();
        short8 af[4], bf[4];
#pragma unroll
        for (int mt = 0; mt < 4; ++mt)
            af[mt] = *reinterpret_cast<const short8*>(&sA[(wm + mt * 16 + l15) * 32 + quad * 8]);
#pragma unroll
        for (int nt = 0; nt < 4; ++nt)
            bf[nt] = *reinterpret_cast<const short8*>(&sB[(wn + nt * 16 + l15) * 32 + quad * 8]);
#pragma unroll
        for (int mt = 0; mt < 4; ++mt)
#pragma unroll
            for (int nt = 0; nt < 4; ++nt)
                acc[mt][nt] = __builtin_amdgcn_mfma_f32_16x16x32_bf16(af[mt], bf[nt], acc[mt][nt], 0, 0, 0);
        __syncthreads();
    }
}

// ---------------- cast fp32 -> bf16 (vectorized x4) ----------------
__global__ void cast_bf16_kernel(const float* __restrict__ src, short* __restrict__ dst, int n4) {
    int i = blockIdx.x * 256 + threadIdx.x;
    if (i >= n4) return;
    float4 v = reinterpret_cast<const float4*>(src)[i];
    short4 o;
    o.x = f2bf(v.x); o.y = f2bf(v.y); o.z = f2bf(v.z); o.w = f2bf(v.w);
    reinterpret_cast<short4*>(dst)[i] = o;
}

// ---------------- transpose qh [B,LQ,D] fp32 -> qhT [B,D,LQ] bf16 ----------------
__global__ void transpose_qh_kernel(const float* __restrict__ qh, short* __restrict__ qhT) {
    __shared__ float tile[32][33];
    const int b = blockIdx.z;
    const int q0 = blockIdx.x * 32, d0 = blockIdx.y * 32;
    const int t = threadIdx.x;
    const int r = t >> 3, c = (t & 7) * 4;
    const float4 v = *reinterpret_cast<const float4*>(qh + ((size_t)b * LQ + q0 + r) * D + d0 + c);
    tile[r][c] = v.x; tile[r][c + 1] = v.y; tile[r][c + 2] = v.z; tile[r][c + 3] = v.w;
    __syncthreads();
    short4 o;
    o.x = f2bf(tile[c][r]); o.y = f2bf(tile[c + 1][r]);
    o.z = f2bf(tile[c + 2][r]); o.w = f2bf(tile[c + 3][r]);
    *reinterpret_cast<short4*>(qhT + ((size_t)b * D + d0 + r) * LQ + q0 + c) = o;
}

// ---------------- GEMM1: query = qh_b * W_b^T + bias -> bf16 ----------------
__global__ __launch_bounds__(256, 2) void gemm1_kernel(
    const short* __restrict__ A, const short* __restrict__ W,
    const float* __restrict__ bias, short* __restrict__ Q) {
    __shared__ short sA[128 * 32];
    __shared__ short sB[128 * 32];
    const int m0 = blockIdx.x * 128, n0 = blockIdx.y * 128;
    const int tid = threadIdx.x;
    const int w = tid >> 6, lane = tid & 63, l15 = lane & 15, quad = lane >> 4;
    const int wm = (w >> 1) * 64, wn = (w & 1) * 64;
    floatx4 acc[4][4];
#pragma unroll
    for (int i = 0; i < 4; ++i)
#pragma unroll
        for (int j = 0; j < 4; ++j) { floatx4 z = {0.f, 0.f, 0.f, 0.f}; acc[i][j] = z; }
    mfma_tile_loop(A, W, D, D, D, m0, n0, sA, sB, tid, acc);
    float bv[4];
#pragma unroll
    for (int nt = 0; nt < 4; ++nt) bv[nt] = bias[n0 + wn + nt * 16 + l15];
#pragma unroll
    for (int mt = 0; mt < 4; ++mt)
#pragma unroll
        for (int r = 0; r < 4; ++r) {
            int row = m0 + wm + mt * 16 + quad * 4 + r;
#pragma unroll
            for (int nt = 0; nt < 4; ++nt)
                Q[(size_t)row * D + n0 + wn + nt * 16 + l15] = f2bf(acc[mt][nt][r] + bv[nt]);
        }
}

// ---------------- ctx pass: copy ctx into out[:, :, 0:768] AND cast to bf16 ----------------
__global__ void ctx_pass_kernel(const float* __restrict__ ctx, float* __restrict__ out,
                                short* __restrict__ ctxb) {
    size_t i = (size_t)blockIdx.x * 256 + threadIdx.x;
    size_t row = i / 192;
    size_t c4 = i % 192;
    float4 v = reinterpret_cast<const float4*>(ctx)[i];
    reinterpret_cast<float4*>(out)[row * 384 + c4] = v;
    short4 o;
    o.x = f2bf(v.x); o.y = f2bf(v.y); o.z = f2bf(v.z); o.w = f2bf(v.w);
    reinterpret_cast<short4*>(ctxb)[i] = o;
}

// ---------------- K1: raw scores S = ctx_b * query_b^T -> bf16 ----------------
__global__ __launch_bounds__(256, 2) void scores_gemm_kernel(
    const short* __restrict__ ctxb, const short* __restrict__ query_b,
    short* __restrict__ S) {
    __shared__ short sA[128 * 32];
    __shared__ short sB[128 * 32];
    const int b = blockIdx.z;
    const int m0 = blockIdx.x * 128, n0 = blockIdx.y * 128;
    const int tid = threadIdx.x;
    const int w = tid >> 6, lane = tid & 63, l15 = lane & 15, quad = lane >> 4;
    const int wm = (w >> 1) * 64, wn = (w & 1) * 64;
    floatx4 acc[4][4];
#pragma unroll
    for (int i = 0; i < 4; ++i)
#pragma unroll
        for (int j = 0; j < 4; ++j) { floatx4 z = {0.f, 0.f, 0.f, 0.f}; acc[i][j] = z; }
    mfma_tile_loop(ctxb + (size_t)b * LC * D, query_b + (size_t)b * LQ * D,
                   D, D, D, m0, n0, sA, sB, tid, acc);
    short* Sb = S + (size_t)b * LC * LQ;
#pragma unroll
    for (int mt = 0; mt < 4; ++mt)
#pragma unroll
        for (int r = 0; r < 4; ++r) {
            size_t row = m0 + wm + mt * 16 + quad * 4 + r;
#pragma unroll
            for (int nt = 0; nt < 4; ++nt)
                Sb[row * LQ + n0 + wn + nt * 16 + l15] = f2bf(acc[mt][nt][r]);
        }
}

// ---------------- softmax in place on S bf16 (scale+mask applied here) ----------------
__global__ __launch_bounds__(256) void softmax_kernel(short* __restrict__ S,
                                                      const int* __restrict__ qmask) {
    __shared__ float redM[4], redS[4];
    const int row = blockIdx.x;              // 0..16383
    const int b = row >> 11;
    const int t = threadIdx.x;
    const int wv = t >> 6, lane = t & 63;
    short* srow = S + (size_t)row * LQ;
    short4 v = reinterpret_cast<short4*>(srow)[t];
    int4 m4 = reinterpret_cast<const int4*>(qmask + (size_t)b * LQ)[t];
    float x0 = m4.x ? bf2f(v.x) * SCALE : -1e30f;
    float x1 = m4.y ? bf2f(v.y) * SCALE : -1e30f;
    float x2 = m4.z ? bf2f(v.z) * SCALE : -1e30f;
    float x3 = m4.w ? bf2f(v.w) * SCALE : -1e30f;
    float m = fmaxf(fmaxf(x0, x1), fmaxf(x2, x3));
#pragma unroll
    for (int off = 1; off < 64; off <<= 1) m = fmaxf(m, __shfl_xor(m, off, 64));
    if (lane == 0) redM[wv] = m;
    __syncthreads();
    m = fmaxf(fmaxf(redM[0], redM[1]), fmaxf(redM[2], redM[3]));
    float p0 = __expf(x0 - m), p1 = __expf(x1 - m), p2 = __expf(x2 - m), p3 = __expf(x3 - m);
    float s = p0 + p1 + p2 + p3;
#pragma unroll
    for (int off = 1; off < 64; off <<= 1) s += __shfl_xor(s, off, 64);
    if (lane == 0) redS[wv] = s;
    __syncthreads();
    s = redS[0] + redS[1] + redS[2] + redS[3];
    const float inv = 1.0f / s;
    short4 o;
    o.x = f2bf(p0 * inv); o.y = f2bf(p1 * inv); o.z = f2bf(p2 * inv); o.w = f2bf(p3 * inv);
    reinterpret_cast<short4*>(srow)[t] = o;
}

// ---------------- K2: attn_out = P * qhT^T -> fp32 into out[...,768:] ----------------
__global__ __launch_bounds__(256, 2) void gemm2_kernel(
    const short* __restrict__ P, const short* __restrict__ qhT,
    float* __restrict__ out) {
    __shared__ short sA[128 * 32];
    __shared__ short sB[128 * 32];
    const int b = blockIdx.z;
    const int m0 = blockIdx.x * 128, n0 = blockIdx.y * 128;
    const int tid = threadIdx.x;
    const int w = tid >> 6, lane = tid & 63, l15 = lane & 15, quad = lane >> 4;
    const int wm = (w >> 1) * 64, wn = (w & 1) * 64;
    floatx4 acc[4][4];
#pragma unroll
    for (int i = 0; i < 4; ++i)
#pragma unroll
        for (int j = 0; j < 4; ++j) { floatx4 z = {0.f, 0.f, 0.f, 0.f}; acc[i][j] = z; }
    mfma_tile_loop(P + (size_t)b * LC * LQ, qhT + (size_t)b * D * LQ,
                   LQ, LQ, LQ, m0, n0, sA, sB, tid, acc);
#pragma unroll
    for (int mt = 0; mt < 4; ++mt)
#pragma unroll
        for (int r = 0; r < 4; ++r) {
            size_t row = (size_t)b * LC + m0 + wm + mt * 16 + quad * 4 + r;
#pragma unroll
            for (int nt = 0; nt < 4; ++nt)
                out[row * 1536 + 768 + n0 + wn + nt * 16 + l15] = acc[mt][nt][r];
        }
}

extern "C" void kernel_launch(void* const* d_in, const int* in_sizes, int n_in,
                              void* d_out, int out_size, void* d_ws, size_t ws_size,
                              hipStream_t stream) {
    const float* ctx = (const float*)d_in[0];
    const float* qh = (const float*)d_in[2];
    const int* qmask = (const int*)d_in[3];
    const float* Wf = (const float*)d_in[4];
    const float* bias = (const float*)d_in[5];
    float* out = (float*)d_out;

    char* ws = (char*)d_ws;
    short* W_b     = (short*)(ws);                  //  1,179,648 B
    short* query_b = (short*)(ws + 1179648);        // 12,582,912 B
    short* qhT     = (short*)(ws + 13762560);       // 12,582,912 B
    short* ctx_b   = (short*)(ws + 26345472);       // 25,165,824 B
    short* S       = (short*)(ws + 51511296);       // 33,554,432 B -> end 85,065,728
    short* qh_b    = (short*)(ws + 51511296);       // alias with S (dead before K1 writes S)

    cast_bf16_kernel<<<576, 256, 0, stream>>>(Wf, W_b, 147456);
    cast_bf16_kernel<<<6144, 256, 0, stream>>>(qh, qh_b, 1572864);
    transpose_qh_kernel<<<dim3(32, 24, 8), 256, 0, stream>>>(qh, qhT);
    gemm1_kernel<<<dim3(64, 6), 256, 0, stream>>>(qh_b, W_b, bias, query_b);
    ctx_pass_kernel<<<12288, 256, 0, stream>>>(ctx, out, ctx_b);
    scores_gemm_kernel<<<dim3(16, 8, 8), 256, 0, stream>>>(ctx_b, query_b, S);
    softmax_kernel<<<16384, 256, 0, stream>>>(S, qmask);
    gemm2_kernel<<<dim3(16, 6, 8), 256, 0, stream>>>(S, qhT, out);
}